// Round 14
// baseline (292.174 us; speedup 1.0000x reference)
//
#include <hip/hip_runtime.h>

// Affine_Linear_Abla_Quat — v10: async J staging via global_load_lds.
// Learned (v3/v4/v6/v7/v9): this compiler ALWAYS re-sinks register load
// batching to ~zero lookahead (VGPR 52 signature), and big register payloads
// spill. So bypass registers: DMA J into LDS with global_load_lds (no dest
// VGPR -> compiler-proof), issue chunk t+1's DMA before GEMM(t) so HBM
// latency hides under ~3000 cyc of MFMA. quat reads J from LDS (~120cyc).
// 256 blocks x 1024 thr (16 waves, 4/SIMD), NCH=8 chunks of Gp=16 pairs.
// LDS: SJ 64KB + TT 73.7KB = 136KB -> 1 block/CU. GEMM = v3's verified math,
// 1 f-strip/wave (16 waves cover F=256), 3 MFMA per k0.

typedef __bf16 bf16_t;
typedef __attribute__((ext_vector_type(8))) __bf16 bf16x8;
typedef __attribute__((ext_vector_type(4))) __bf16 bf16x4;
typedef __attribute__((ext_vector_type(4))) float f32x4;

constexpr int Dd  = 256;   // D == F
constexpr int Gp  = 16;    // pairs per chunk -> M = 48
constexpr int NCH = 8;     // chunks per block
constexpr int TPB = 1024;  // 16 waves

__device__ __forceinline__ bf16_t to_bf16(float f) {
    unsigned u = __builtin_bit_cast(unsigned, f);
    u += 0x7FFFu + ((u >> 16) & 1u);          // RNE
    unsigned short h = (unsigned short)(u >> 16);
    return __builtin_bit_cast(bf16_t, h);
}

// swizzled element index into TT: row-major [48][768], 16B granule XOR (row&7)
__device__ __forceinline__ int swz(int row, int k) {
    return row * 768 + (k ^ ((row & 7) << 3));
}

// ---- prologue: A,B,C (f32 256x256) -> W bf16 [3][256][256] in d_ws ----
__global__ __launch_bounds__(256)
void convert_w_kernel(const float* __restrict__ A, const float* __restrict__ B,
                      const float* __restrict__ C, bf16_t* __restrict__ W)
{
    const int e4 = (blockIdx.x * 256 + threadIdx.x) * 4;
    const float* src;
    if (e4 < 65536)        src = A + e4;
    else if (e4 < 131072)  src = B + (e4 - 65536);
    else                   src = C + (e4 - 131072);
    const float4 v = *reinterpret_cast<const float4*>(src);
    bf16x4 o;
    o[0] = to_bf16(v.x); o[1] = to_bf16(v.y); o[2] = to_bf16(v.z); o[3] = to_bf16(v.w);
    *reinterpret_cast<bf16x4*>(W + e4) = o;
}

// ------------------------------ main kernel ------------------------------
__global__ __launch_bounds__(TPB, 4)
void alaq_v10_kernel(const float* __restrict__ X, const float* __restrict__ J,
                     const bf16_t* __restrict__ W, float* __restrict__ Y)
{
    __shared__ float  SJ[Gp * Dd * 4];   // 65,536 B raw J for one chunk
    __shared__ bf16_t TT[48 * 768];      // 73,728 B terms

    const int tid = threadIdx.x;
    const int w   = tid >> 6;            // wave 0..15
    const int l   = tid & 63;
    const int lr  = l & 15;
    const int lq  = l >> 4;
    const long pair0 = (long)blockIdx.x * (Gp * NCH);

    // ---- async DMA of chunk t's J into SJ (identity layout) ----
    auto DMA_J = [&](int t) {
        const char* jsrc = (const char*)J + (pair0 + (long)t * Gp) * Dd * 16;
        char* sdst = (char*)SJ;
        #pragma unroll
        for (int i = 0; i < 4; ++i) {
            const int winst = w * 4 + i;               // 0..63, wave-uniform
            __builtin_amdgcn_global_load_lds(
                (const __attribute__((address_space(1))) void*)(jsrc + winst * 1024 + l * 16),
                (__attribute__((address_space(3))) void*)(sdst + winst * 1024),
                16, 0, 0);
        }
    };

    // W fragment base: wave owns f-strip w (f = w*16 + lr)
    const bf16_t* Wf = W + (w * 16 + lr) * 256 + (lq << 3);
    const int swzmask = (lr & 7) << 3;

    // ---- prologue: DMA chunk 0, drain, barrier ----
    DMA_J(0);
    asm volatile("s_waitcnt vmcnt(0)" ::: "memory");
    __syncthreads();

    for (int t = 0; t < NCH; ++t) {
        const long pb = pair0 + (long)t * Gp;          // first pair of chunk

        // ---------------- quat: SJ + X -> TT ----------------
        #pragma unroll
        for (int rr = 0; rr < 4; ++rr) {
            const int idx = rr * TPB + tid;            // 0..4095
            const int p = idx >> 8;
            const int e = idx & 255;

            const f32x4 q = *reinterpret_cast<const f32x4*>(&SJ[idx * 4]);
            const float* xp = X + (pb * Dd + idx) * 3;
            const float x0 = xp[0], x1 = xp[1], x2 = xp[2];

            const float nsq = q[0]*q[0] + q[1]*q[1] + q[2]*q[2] + q[3]*q[3];
            const float inv = 1.0f / fmaxf(sqrtf(nsq), 1e-12f);
            const float qx = q[0]*inv, qy = q[1]*inv, qz = q[2]*inv, qw = q[3]*inv;
            const float s = 2.0f / (qw*qw + qx*qx + qy*qy + qz*qz);

            const float r00 = 1.0f - s*(qy*qy + qz*qz);
            const float r01 = s*(qx*qy - qz*qw);
            const float r02 = s*(qx*qz + qy*qw);
            const float r10 = s*(qx*qy + qz*qw);
            const float r11 = 1.0f - s*(qx*qx + qz*qz);
            const float r12 = s*(qy*qz - qx*qw);
            const float r20 = s*(qx*qz - qy*qw);
            const float r21 = s*(qy*qz + qx*qw);
            const float r22 = 1.0f - s*(qx*qx + qy*qy);

            const float rt0 = r00*x0 + r10*x1 + r20*x2;
            const float rt1 = r01*x0 + r11*x1 + r21*x2;
            const float rt2 = r02*x0 + r12*x1 + r22*x2;

            const int row = p * 3;
            TT[swz(row    ,       e)] = to_bf16(r00*rt0 + r01*rt1);
            TT[swz(row + 1,       e)] = to_bf16(r10*rt0 + r11*rt1);
            TT[swz(row + 2,       e)] = to_bf16(r20*rt0 + r21*rt1);
            TT[swz(row    , 256 + e)] = to_bf16(r01*rt0 - r00*rt1);
            TT[swz(row + 1, 256 + e)] = to_bf16(r11*rt0 - r10*rt1);
            TT[swz(row + 2, 256 + e)] = to_bf16(r21*rt0 - r20*rt1);
            TT[swz(row    , 512 + e)] = to_bf16(r02*rt2);
            TT[swz(row + 1, 512 + e)] = to_bf16(r12*rt2);
            TT[swz(row + 2, 512 + e)] = to_bf16(r22*rt2);
        }
        __syncthreads();   // SJ reads done + TT ready

        // ---- issue next chunk's J DMA; flies under the GEMM ----
        if (t + 1 < NCH) DMA_J(t + 1);

        // ---------------- GEMM: TT x W -> Y ----------------
        f32x4 acc[3] = {};

        #pragma unroll
        for (int k0 = 0; k0 < 24; ++k0) {
            const int term = k0 >> 3;
            const int ebo  = (k0 & 7) << 5;
            const bf16x8 b = *reinterpret_cast<const bf16x8*>(Wf + (term << 16) + ebo);

            const int kswz = (((k0 << 5) + (lq << 3)) ^ swzmask);
            const bf16x8 a0 = *reinterpret_cast<const bf16x8*>(&TT[      lr  * 768 + kswz]);
            const bf16x8 a1 = *reinterpret_cast<const bf16x8*>(&TT[(16 + lr) * 768 + kswz]);
            const bf16x8 a2 = *reinterpret_cast<const bf16x8*>(&TT[(32 + lr) * 768 + kswz]);

            acc[0] = __builtin_amdgcn_mfma_f32_16x16x32_bf16(a0, b, acc[0], 0, 0, 0);
            acc[1] = __builtin_amdgcn_mfma_f32_16x16x32_bf16(a1, b, acc[1], 0, 0, 0);
            acc[2] = __builtin_amdgcn_mfma_f32_16x16x32_bf16(a2, b, acc[2], 0, 0, 0);
        }

        // store Y for chunk t: f-strip w, rows m = mi*16 + lq*4 + r
        const int f = w * 16 + lr;
        #pragma unroll
        for (int mi = 0; mi < 3; ++mi) {
            #pragma unroll
            for (int r = 0; r < 4; ++r) {
                const int m = mi * 16 + lq * 4 + r;    // 0..47
                const int p = m / 3;
                const int i = m - p * 3;
                Y[(pb + p) * 768 + f * 3 + i] = acc[mi][r];
            }
        }

        // drain DMA (+stores) so SJ(t+1) is complete for everyone, then sync
        asm volatile("s_waitcnt vmcnt(0)" ::: "memory");
        __syncthreads();
    }
}

extern "C" void kernel_launch(void* const* d_in, const int* in_sizes, int n_in,
                              void* d_out, int out_size, void* d_ws, size_t ws_size,
                              hipStream_t stream) {
    const float* X  = (const float*)d_in[0];
    const float* J  = (const float*)d_in[1];
    const float* A  = (const float*)d_in[2];
    const float* B  = (const float*)d_in[3];
    const float* Cm = (const float*)d_in[4];
    float* Y = (float*)d_out;
    bf16_t* W = (bf16_t*)d_ws;    // 393,216 B

    convert_w_kernel<<<192, 256, 0, stream>>>(A, B, Cm, W);

    const int nbn = in_sizes[1] / (Dd * 4);       // 32768
    const int blocks = nbn / (Gp * NCH);          // 256
    alaq_v10_kernel<<<blocks, TPB, 0, stream>>>(X, J, W, Y);
}